// Round 11
// baseline (765.242 us; speedup 1.0000x reference)
//
#include <hip/hip_runtime.h>
#include <hip/hip_bf16.h>

#define IN_DIM 1024
#define DK 512
#define DV 512
#define NQ 8192
#define NKV 8192

typedef _Float16 f16x8 __attribute__((ext_vector_type(8)));
typedef _Float16 f16x4 __attribute__((ext_vector_type(4)));
typedef float f32x4 __attribute__((ext_vector_type(4)));

// ---------------- projection: out = A @ W^T + b -----------------------------
// Outputs in MFMA-fragment-major layout (frag = 64 lanes x 16 B = 1 KB):
//  Q'/K': frag fi = n_tile*16 + k_step; element [n = tile*16+l16][k = step*32+quad*8+j]
//  V'   : frag fi = (chunk*32 + dv_tile)*2 + kst;
//         element [key = chunk*64+kst*32+quad*8+j][dv = dv_tile*16+l16]
__global__ __launch_bounds__(256, 2) void proj_kernel(
    const float* __restrict__ qin, const float* __restrict__ kin, const float* __restrict__ vin,
    const float* __restrict__ Wq, const float* __restrict__ bq,
    const float* __restrict__ Wk, const float* __restrict__ bk,
    const float* __restrict__ Wv, const float* __restrict__ bv,
    _Float16* __restrict__ Qp, _Float16* __restrict__ Kp, _Float16* __restrict__ Vp)
{
    const int z = blockIdx.z;
    const float* A  = (z == 0) ? qin : (z == 1) ? kin : vin;
    const float* W  = (z == 0) ? Wq  : (z == 1) ? Wk  : Wv;
    const float* bi = (z == 0) ? bq  : (z == 1) ? bk  : bv;

    __shared__ __align__(16) char psm[73728];
    _Float16 (*As)[128][72] = (_Float16(*)[128][72])psm;           // [2][128][72]
    _Float16 (*Bs)[128][72] = (_Float16(*)[128][72])(psm + 36864);
    _Float16* trans = (_Float16*)psm;   // [128][152] = 38912 B, reused post-loop

    const int tid = threadIdx.x;
    const int rowbase = blockIdx.y * 128;
    const int colbase = blockIdx.x * 128;
    const int wave = tid >> 6;
    const int lane = tid & 63;
    const int quad = lane >> 4;
    const int l16  = lane & 15;
    const int wrow = (wave & 1) * 64;
    const int wcol = (wave >> 1) * 64;

    float4 ra[8], rb[8];
    auto ld = [&](int kc) {
#pragma unroll
        for (int i = 0; i < 8; ++i) {
            int idx = tid + i * 256;
            int row = idx >> 4, c4 = idx & 15;
            ra[i] = *(const float4*)&A[(size_t)(rowbase + row) * IN_DIM + kc * 64 + c4 * 4];
            rb[i] = *(const float4*)&W[(size_t)(colbase + row) * IN_DIM + kc * 64 + c4 * 4];
        }
    };
    auto st = [&](int buf) {
#pragma unroll
        for (int i = 0; i < 8; ++i) {
            int idx = tid + i * 256;
            int row = idx >> 4, c4 = idx & 15;
            f16x4 pa, pb;
            pa[0] = (_Float16)ra[i].x; pa[1] = (_Float16)ra[i].y;
            pa[2] = (_Float16)ra[i].z; pa[3] = (_Float16)ra[i].w;
            pb[0] = (_Float16)rb[i].x; pb[1] = (_Float16)rb[i].y;
            pb[2] = (_Float16)rb[i].z; pb[3] = (_Float16)rb[i].w;
            *(f16x4*)&As[buf][row][c4 * 4] = pa;
            *(f16x4*)&Bs[buf][row][c4 * 4] = pb;
        }
    };

    f32x4 acc[4][4];
#pragma unroll
    for (int r = 0; r < 4; ++r)
#pragma unroll
        for (int c = 0; c < 4; ++c) acc[r][c] = (f32x4)(0.0f);

    ld(0); st(0); ld(1);
    __syncthreads();

    for (int kc = 0; kc < 16; ++kc) {
        const int buf = kc & 1;
#pragma unroll
        for (int ks = 0; ks < 2; ++ks) {
            f16x8 af[4], bfr[4];
#pragma unroll
            for (int r = 0; r < 4; ++r)
                af[r] = *(const f16x8*)&As[buf][wrow + r * 16 + l16][ks * 32 + quad * 8];
#pragma unroll
            for (int c = 0; c < 4; ++c)
                bfr[c] = *(const f16x8*)&Bs[buf][wcol + c * 16 + l16][ks * 32 + quad * 8];
#pragma unroll
            for (int r = 0; r < 4; ++r)
#pragma unroll
                for (int c = 0; c < 4; ++c)
                    acc[r][c] = __builtin_amdgcn_mfma_f32_16x16x32_f16(af[r], bfr[c], acc[r][c], 0, 0, 0);
        }
        if (kc + 1 < 16) st(buf ^ 1);
        if (kc + 2 < 16) ld(kc + 2);
        __syncthreads();
    }
    // loop-ending barrier: LDS now dead, reuse as `trans`

    const int S = 152;   // row stride (f16); 304 B -> 2-way max bank aliasing
    if (z < 2) {
        _Float16* outp = (z == 0) ? Qp : Kp;
#pragma unroll
        for (int c = 0; c < 4; ++c) {
            int col = wcol + c * 16 + l16;          // local dk
            float bval = bi[colbase + col];
#pragma unroll
            for (int r = 0; r < 4; ++r)
#pragma unroll
                for (int g = 0; g < 4; ++g) {
                    int row = wrow + r * 16 + quad * 4 + g;   // local n (q or key)
                    trans[row * S + col] = (_Float16)(acc[r][c][g] + bval);
                }
        }
        __syncthreads();
#pragma unroll
        for (int i = 0; i < 2; ++i)
#pragma unroll
            for (int stp = 0; stp < 4; ++stp) {
                int tl = wave * 2 + i;
                f16x8 v = *(const f16x8*)&trans[(tl * 16 + l16) * S + stp * 32 + quad * 8];
                size_t fi = (size_t)((blockIdx.y * 8 + tl) * 16 + (blockIdx.x * 4 + stp));
                *(f16x8*)&outp[fi * 512 + lane * 8] = v;
            }
    } else {
        // stage TRANSPOSED: trans[dv][key] so V' frag reads are contiguous
#pragma unroll
        for (int c = 0; c < 4; ++c) {
            int dv = wcol + c * 16 + l16;
            float bval = bi[colbase + dv];
#pragma unroll
            for (int r = 0; r < 4; ++r)
#pragma unroll
                for (int g = 0; g < 4; ++g) {
                    int key = wrow + r * 16 + quad * 4 + g;
                    trans[dv * S + key] = (_Float16)(acc[r][c][g] + bval);
                }
        }
        __syncthreads();
#pragma unroll
        for (int i = 0; i < 2; ++i)
#pragma unroll
            for (int chl = 0; chl < 2; ++chl)
#pragma unroll
                for (int kst = 0; kst < 2; ++kst) {
                    int tdl = wave * 2 + i;
                    f16x8 v = *(const f16x8*)&trans[(tdl * 16 + l16) * S + chl * 64 + kst * 32 + quad * 8];
                    size_t fi = ((size_t)(blockIdx.y * 2 + chl) * 32 + (blockIdx.x * 8 + tdl)) * 2 + kst;
                    *(f16x8*)&Vp[fi * 512 + lane * 8] = v;
                }
    }
}

// ---- flash attention v11: swapped QK^T + Q frags hoisted to registers ----
// R10 confirmed the LDS-pipe census (223 us, MfmaUtil 26.8%). Remaining
// dominant DS term: 256 ds_read_b128 of Q frags per chunk (~3.1 of 8.4 kcyc)
// -- but Q frags are LOOP-INVARIANT. Hoist qf[2][16] (128 VGPRs) to regs,
// loaded once from global; delete the Q LDS tile (-32 KB) and the prologue
// barrier. S^T is now pure register MFMA. Nominal reg demand 288 > 256 cap;
// compiler sinks kf/vf toward uses (benign, proven R1/R3/R6: pinning loads
// early gained nothing). Occupancy is grid-capped (256 blocks / 256 CUs =
// 8 waves/CU) so register spend is free.
// Spill canary: WRITE_SIZE must stay 16.4 MB (out only).
__global__ __launch_bounds__(512, 2) void flash_kernel(
    const _Float16* __restrict__ Qp, const _Float16* __restrict__ Kp,
    const _Float16* __restrict__ Vp, float* __restrict__ outp)
{
    __shared__ __align__(16) _Float16 Ps[2][32][72];  // two 64-key P halves
    __shared__ float Smax2[32][12];                   // cols 0..7 used (8 waves)
    __shared__ float Ssum2[32][12];
    __shared__ float lfin[32];

    const int tid  = threadIdx.x;
    const int w    = tid >> 6;          // 0..7
    const int lane = tid & 63;
    const int quad = lane >> 4;
    const int l16  = lane & 15;
    const int qbase = blockIdx.x * 32;

    // ---- Q fragments in registers, whole DK, 2 q-bands: 128 VGPRs, one-time
    f16x8 qf[2][16];
    {
        const _Float16* qp = Qp + (size_t)qbase * 512 + lane * 8;
#pragma unroll
        for (int qt = 0; qt < 2; ++qt)
#pragma unroll
            for (int stp = 0; stp < 16; ++stp)
                qf[qt][stp] = *(const f16x8*)(qp + (size_t)(qt * 16 + stp) * 512);
    }

    // per-lane online stats for q0 = l16 and q1 = 16+l16 (duplicated across quads)
    float mreg0 = -1e30f, mreg1 = -1e30f, lreg0 = 0.0f, lreg1 = 0.0f;
    f32x4 oacc[2][4];
#pragma unroll
    for (int qt = 0; qt < 2; ++qt)
#pragma unroll
        for (int t = 0; t < 4; ++t) oacc[qt][t] = (f32x4)(0.0f);

    // ---- prologue: K frags for chunk 0 (wave's 16-key slice, full DK)
    const _Float16* kfp = Kp + (size_t)w * 16 * 512 + lane * 8;   // + ch*65536
    f16x8 kf[16];
#pragma unroll
    for (int stp = 0; stp < 16; ++stp)
        kf[stp] = *(const f16x8*)(kfp + (size_t)stp * 512);

    f16x8 vf[16];

    for (int ch = 0; ch < 64; ++ch) {
        // ---- issue V loads for THIS chunk (consumed at PV, 2 barriers away)
        // wave-w dv slice = w*64 -> frag base w*8; chunk base ch*128 frags;
        // frag enumeration h*64 + t*2 + ks (h = 64-key half)
        const _Float16* vp = Vp + ((size_t)ch * 128 + w * 8) * 512 + lane * 8;
#pragma unroll
        for (int h = 0; h < 2; ++h)
#pragma unroll
            for (int t = 0; t < 4; ++t)
#pragma unroll
                for (int ks = 0; ks < 2; ++ks)
                    vf[h * 8 + t * 2 + ks] = *(const f16x8*)(vp + (size_t)(h * 64 + t * 2 + ks) * 512);

        // ---- S^T: 16 keys (wave slice) x 32 q; kf as A, Q regs as B
        f32x4 st0 = (f32x4)(0.0f), st1 = (f32x4)(0.0f);
        __builtin_amdgcn_s_setprio(1);
#pragma unroll
        for (int stp = 0; stp < 16; ++stp) {
            st0 = __builtin_amdgcn_mfma_f32_16x16x32_f16(kf[stp], qf[0][stp], st0, 0, 0, 0);
            st1 = __builtin_amdgcn_mfma_f32_16x16x32_f16(kf[stp], qf[1][stp], st1, 0, 0, 0);
        }
        __builtin_amdgcn_s_setprio(0);
        // lane holds S[key = w*16 + quad*4 + r][q = band*16 + l16], r = 0..3

        // ---- slice max over 16 keys: in-lane over 4 regs + butterfly over quads
        float ms0 = fmaxf(fmaxf(st0[0], st0[1]), fmaxf(st0[2], st0[3]));
        float ms1 = fmaxf(fmaxf(st1[0], st1[1]), fmaxf(st1[2], st1[3]));
        ms0 = fmaxf(ms0, __shfl_xor(ms0, 16)); ms0 = fmaxf(ms0, __shfl_xor(ms0, 32));
        ms1 = fmaxf(ms1, __shfl_xor(ms1, 16)); ms1 = fmaxf(ms1, __shfl_xor(ms1, 32));
        if (lane < 16) { Smax2[lane][w] = ms0; Smax2[16 + lane][w] = ms1; }

        // ---- prefetch next K (kf consumed by S^T above)
        if (ch + 1 < 64) {
            const _Float16* kp = kfp + (size_t)(ch + 1) * 65536;
#pragma unroll
            for (int stp = 0; stp < 16; ++stp)
                kf[stp] = *(const f16x8*)(kp + (size_t)stp * 512);
        }

        asm volatile("s_waitcnt lgkmcnt(0)" ::: "memory");
        __builtin_amdgcn_s_barrier();      // B1: Smax2 ready (no vmcnt drain)

        // ---- combine max (8-way over waves), alpha, exp, pack P^T, slice sums
        float4 a0 = *(const float4*)&Smax2[l16][0];
        float4 b0 = *(const float4*)&Smax2[l16][4];
        float mt0 = fmaxf(fmaxf(fmaxf(a0.x, a0.y), fmaxf(a0.z, a0.w)),
                          fmaxf(fmaxf(b0.x, b0.y), fmaxf(b0.z, b0.w)));
        float4 a1 = *(const float4*)&Smax2[16 + l16][0];
        float4 b1 = *(const float4*)&Smax2[16 + l16][4];
        float mt1 = fmaxf(fmaxf(fmaxf(a1.x, a1.y), fmaxf(a1.z, a1.w)),
                          fmaxf(fmaxf(b1.x, b1.y), fmaxf(b1.z, b1.w)));
        float mn0 = fmaxf(mreg0, mt0);
        float mn1 = fmaxf(mreg1, mt1);
        float alpha0 = __expf(mreg0 - mn0); mreg0 = mn0; lreg0 *= alpha0;
        float alpha1 = __expf(mreg1 - mn1); mreg1 = mn1; lreg1 *= alpha1;

        float p00 = __expf(st0[0] - mn0), p01 = __expf(st0[1] - mn0);
        float p02 = __expf(st0[2] - mn0), p03 = __expf(st0[3] - mn0);
        float p10 = __expf(st1[0] - mn1), p11 = __expf(st1[1] - mn1);
        float p12 = __expf(st1[2] - mn1), p13 = __expf(st1[3] - mn1);
        f16x4 pp0, pp1;
        pp0[0] = (_Float16)p00; pp0[1] = (_Float16)p01;
        pp0[2] = (_Float16)p02; pp0[3] = (_Float16)p03;
        pp1[0] = (_Float16)p10; pp1[1] = (_Float16)p11;
        pp1[2] = (_Float16)p12; pp1[3] = (_Float16)p13;
        // P[q][key]: row = band*16 + l16, col = (w&3)*16 + quad*4 + r  (contig!)
        *(f16x4*)&Ps[w >> 2][l16][(w & 3) * 16 + quad * 4]      = pp0;
        *(f16x4*)&Ps[w >> 2][16 + l16][(w & 3) * 16 + quad * 4] = pp1;

        float ts0 = (p00 + p01) + (p02 + p03);
        float ts1 = (p10 + p11) + (p12 + p13);
        ts0 += __shfl_xor(ts0, 16); ts0 += __shfl_xor(ts0, 32);
        ts1 += __shfl_xor(ts1, 16); ts1 += __shfl_xor(ts1, 32);
        if (lane < 16) { Ssum2[lane][w] = ts0; Ssum2[16 + lane][w] = ts1; }

        // ---- carry alpha to oacc rows (q = quad*4 + g): src lane = quad*20+g
        float ao0[4], ao1[4];
#pragma unroll
        for (int g = 0; g < 4; ++g) {
            ao0[g] = __shfl(alpha0, quad * 20 + g);
            ao1[g] = __shfl(alpha1, quad * 20 + g);
        }
#pragma unroll
        for (int t = 0; t < 4; ++t)
#pragma unroll
            for (int g = 0; g < 4; ++g) {
                oacc[0][t][g] *= ao0[g];
                oacc[1][t][g] *= ao1[g];
            }

        asm volatile("s_waitcnt lgkmcnt(0)" ::: "memory");
        __builtin_amdgcn_s_barrier();      // B2: Ps/Ssum2 ready (no vmcnt drain)

        // ---- l finalize (lreg already scaled by alpha pre-B2)
        {
            float4 sa = *(const float4*)&Ssum2[l16][0];
            float4 sb = *(const float4*)&Ssum2[l16][4];
            lreg0 += (sa.x + sa.y) + (sa.z + sa.w) + (sb.x + sb.y) + (sb.z + sb.w);
            float4 sc = *(const float4*)&Ssum2[16 + l16][0];
            float4 sd = *(const float4*)&Ssum2[16 + l16][4];
            lreg1 += (sc.x + sc.y) + (sc.z + sc.w) + (sd.x + sd.y) + (sd.z + sd.w);
        }

        // ---- PV: P A-frags from LDS (row = q), V frags from registers
        __builtin_amdgcn_s_setprio(1);
#pragma unroll
        for (int kst = 0; kst < 4; ++kst) {
            f16x8 pa0 = *(const f16x8*)&Ps[kst >> 1][l16][(kst & 1) * 32 + quad * 8];
            f16x8 pa1 = *(const f16x8*)&Ps[kst >> 1][16 + l16][(kst & 1) * 32 + quad * 8];
            const int vb = (kst >> 1) * 8 + (kst & 1);
#pragma unroll
            for (int t = 0; t < 4; ++t) {
                oacc[0][t] = __builtin_amdgcn_mfma_f32_16x16x32_f16(pa0, vf[vb + t * 2], oacc[0][t], 0, 0, 0);
                oacc[1][t] = __builtin_amdgcn_mfma_f32_16x16x32_f16(pa1, vf[vb + t * 2], oacc[1][t], 0, 0, 0);
            }
        }
        __builtin_amdgcn_s_setprio(0);
    }

    // ---- epilogue: transpose l (stats live at q=l16; O rows are q=quad*4+g)
    if (w == 0 && lane < 16) { lfin[lane] = lreg0; lfin[16 + lane] = lreg1; }
    __syncthreads();

    const float norm = 0.044194173824159216f;   // 1/sqrt(512)
#pragma unroll
    for (int qt = 0; qt < 2; ++qt)
#pragma unroll
        for (int g = 0; g < 4; ++g) {
            const int row = qbase + qt * 16 + quad * 4 + g;
            const float sc = norm / lfin[qt * 16 + quad * 4 + g];
#pragma unroll
            for (int t = 0; t < 4; ++t)
                outp[(size_t)row * 512 + w * 64 + t * 16 + l16] = oacc[qt][t][g] * sc;
        }
}

extern "C" void kernel_launch(void* const* d_in, const int* in_sizes, int n_in,
                              void* d_out, int out_size, void* d_ws, size_t ws_size,
                              hipStream_t stream) {
    const float* q  = (const float*)d_in[0];
    const float* k  = (const float*)d_in[1];
    const float* v  = (const float*)d_in[2];
    const float* Wq = (const float*)d_in[3];
    const float* bq = (const float*)d_in[4];
    const float* Wk = (const float*)d_in[5];
    const float* bk = (const float*)d_in[6];
    const float* Wv = (const float*)d_in[7];
    const float* bv = (const float*)d_in[8];

    _Float16* Qp = (_Float16*)d_ws;                 // 8 MB, frag-major
    _Float16* Kp = Qp + (size_t)NQ * DK;            // 8 MB, frag-major
    _Float16* Vp = Kp + (size_t)NKV * DK;           // 8 MB, frag-major
    float* outp = (float*)d_out;

    proj_kernel<<<dim3(DK / 128, NQ / 128, 3), 256, 0, stream>>>(
        q, k, v, Wq, bq, Wk, bk, Wv, bv, Qp, Kp, Vp);
    flash_kernel<<<dim3(NQ / 32), 512, 0, stream>>>(Qp, Kp, Vp, outp);
}

// Round 13
// 374.972 us; speedup vs baseline: 2.0408x; 2.0408x over previous
//
#include <hip/hip_runtime.h>
#include <hip/hip_bf16.h>

#define IN_DIM 1024
#define DK 512
#define DV 512
#define NQ 8192
#define NKV 8192

typedef _Float16 f16x8 __attribute__((ext_vector_type(8)));
typedef _Float16 f16x4 __attribute__((ext_vector_type(4)));
typedef float f32x4 __attribute__((ext_vector_type(4)));

// ---------------- projection: out = A @ W^T + b -----------------------------
// Outputs in MFMA-fragment-major layout (frag = 64 lanes x 16 B = 1 KB):
//  Q'/K': frag fi = n_tile*16 + k_step; element [n = tile*16+l16][k = step*32+quad*8+j]
//  V'   : frag fi = (chunk*32 + dv_tile)*2 + kst;
//         element [key = chunk*64+kst*32+quad*8+j][dv = dv_tile*16+l16]
__global__ __launch_bounds__(256, 2) void proj_kernel(
    const float* __restrict__ qin, const float* __restrict__ kin, const float* __restrict__ vin,
    const float* __restrict__ Wq, const float* __restrict__ bq,
    const float* __restrict__ Wk, const float* __restrict__ bk,
    const float* __restrict__ Wv, const float* __restrict__ bv,
    _Float16* __restrict__ Qp, _Float16* __restrict__ Kp, _Float16* __restrict__ Vp)
{
    const int z = blockIdx.z;
    const float* A  = (z == 0) ? qin : (z == 1) ? kin : vin;
    const float* W  = (z == 0) ? Wq  : (z == 1) ? Wk  : Wv;
    const float* bi = (z == 0) ? bq  : (z == 1) ? bk  : bv;

    __shared__ __align__(16) char psm[73728];
    _Float16 (*As)[128][72] = (_Float16(*)[128][72])psm;           // [2][128][72]
    _Float16 (*Bs)[128][72] = (_Float16(*)[128][72])(psm + 36864);
    _Float16* trans = (_Float16*)psm;   // [128][152] = 38912 B, reused post-loop

    const int tid = threadIdx.x;
    const int rowbase = blockIdx.y * 128;
    const int colbase = blockIdx.x * 128;
    const int wave = tid >> 6;
    const int lane = tid & 63;
    const int quad = lane >> 4;
    const int l16  = lane & 15;
    const int wrow = (wave & 1) * 64;
    const int wcol = (wave >> 1) * 64;

    float4 ra[8], rb[8];
    auto ld = [&](int kc) {
#pragma unroll
        for (int i = 0; i < 8; ++i) {
            int idx = tid + i * 256;
            int row = idx >> 4, c4 = idx & 15;
            ra[i] = *(const float4*)&A[(size_t)(rowbase + row) * IN_DIM + kc * 64 + c4 * 4];
            rb[i] = *(const float4*)&W[(size_t)(colbase + row) * IN_DIM + kc * 64 + c4 * 4];
        }
    };
    auto st = [&](int buf) {
#pragma unroll
        for (int i = 0; i < 8; ++i) {
            int idx = tid + i * 256;
            int row = idx >> 4, c4 = idx & 15;
            f16x4 pa, pb;
            pa[0] = (_Float16)ra[i].x; pa[1] = (_Float16)ra[i].y;
            pa[2] = (_Float16)ra[i].z; pa[3] = (_Float16)ra[i].w;
            pb[0] = (_Float16)rb[i].x; pb[1] = (_Float16)rb[i].y;
            pb[2] = (_Float16)rb[i].z; pb[3] = (_Float16)rb[i].w;
            *(f16x4*)&As[buf][row][c4 * 4] = pa;
            *(f16x4*)&Bs[buf][row][c4 * 4] = pb;
        }
    };

    f32x4 acc[4][4];
#pragma unroll
    for (int r = 0; r < 4; ++r)
#pragma unroll
        for (int c = 0; c < 4; ++c) acc[r][c] = (f32x4)(0.0f);

    ld(0); st(0); ld(1);
    __syncthreads();

    for (int kc = 0; kc < 16; ++kc) {
        const int buf = kc & 1;
#pragma unroll
        for (int ks = 0; ks < 2; ++ks) {
            f16x8 af[4], bfr[4];
#pragma unroll
            for (int r = 0; r < 4; ++r)
                af[r] = *(const f16x8*)&As[buf][wrow + r * 16 + l16][ks * 32 + quad * 8];
#pragma unroll
            for (int c = 0; c < 4; ++c)
                bfr[c] = *(const f16x8*)&Bs[buf][wcol + c * 16 + l16][ks * 32 + quad * 8];
#pragma unroll
            for (int r = 0; r < 4; ++r)
#pragma unroll
                for (int c = 0; c < 4; ++c)
                    acc[r][c] = __builtin_amdgcn_mfma_f32_16x16x32_f16(af[r], bfr[c], acc[r][c], 0, 0, 0);
        }
        if (kc + 1 < 16) st(buf ^ 1);
        if (kc + 2 < 16) ld(kc + 2);
        __syncthreads();
    }
    // loop-ending barrier: LDS now dead, reuse as `trans`

    const int S = 152;   // row stride (f16); 304 B -> 2-way max bank aliasing
    if (z < 2) {
        _Float16* outp = (z == 0) ? Qp : Kp;
#pragma unroll
        for (int c = 0; c < 4; ++c) {
            int col = wcol + c * 16 + l16;          // local dk
            float bval = bi[colbase + col];
#pragma unroll
            for (int r = 0; r < 4; ++r)
#pragma unroll
                for (int g = 0; g < 4; ++g) {
                    int row = wrow + r * 16 + quad * 4 + g;   // local n (q or key)
                    trans[row * S + col] = (_Float16)(acc[r][c][g] + bval);
                }
        }
        __syncthreads();
#pragma unroll
        for (int i = 0; i < 2; ++i)
#pragma unroll
            for (int stp = 0; stp < 4; ++stp) {
                int tl = wave * 2 + i;
                f16x8 v = *(const f16x8*)&trans[(tl * 16 + l16) * S + stp * 32 + quad * 8];
                size_t fi = (size_t)((blockIdx.y * 8 + tl) * 16 + (blockIdx.x * 4 + stp));
                *(f16x8*)&outp[fi * 512 + lane * 8] = v;
            }
    } else {
        // stage TRANSPOSED: trans[dv][key] so V' frag reads are contiguous
#pragma unroll
        for (int c = 0; c < 4; ++c) {
            int dv = wcol + c * 16 + l16;
            float bval = bi[colbase + dv];
#pragma unroll
            for (int r = 0; r < 4; ++r)
#pragma unroll
                for (int g = 0; g < 4; ++g) {
                    int key = wrow + r * 16 + quad * 4 + g;
                    trans[dv * S + key] = (_Float16)(acc[r][c][g] + bval);
                }
        }
        __syncthreads();
#pragma unroll
        for (int i = 0; i < 2; ++i)
#pragma unroll
            for (int chl = 0; chl < 2; ++chl)
#pragma unroll
                for (int kst = 0; kst < 2; ++kst) {
                    int tdl = wave * 2 + i;
                    f16x8 v = *(const f16x8*)&trans[(tdl * 16 + l16) * S + chl * 64 + kst * 32 + quad * 8];
                    size_t fi = ((size_t)(blockIdx.y * 2 + chl) * 32 + (blockIdx.x * 8 + tdl)) * 2 + kst;
                    *(f16x8*)&Vp[fi * 512 + lane * 8] = v;
                }
    }
}

// ---- flash attention v13: R10 base + SINGLE barrier per chunk -------------
// R11/R12 (Q-hoist branch): abandoned -- both forms hit the register-budget
// cliff (remat storm / NaN). R10 (223 us, MfmaUtil 26.8%) is the green base;
// its remaining structural cost: TWO barrier convoys per chunk (~1.3-1.8
// kcyc each of 8.4).
// Change: each wave computes P with its OWN slice max m_w (no cross-wave
// wait), writes P + m_w + slice-sum, then ONE barrier. Post-barrier, lanes
// read the 8 m_w's, form mn, and apply s_w = exp(m_w - mn) per P-fragment
// during PV -- each pa f16x8 comes from exactly one source wave:
// w' = 2*kst + (lane>=32) (from the P column layout), so the fix-up is one
// scalar x f16x8 multiply. l = l*alpha + sum_w s_w*ts_w.
// Ps/stats parity double-buffered: with one barrier/chunk a fast wave can
// write chunk ch+1's P while a slow wave reads chunk ch's -- parity buffers
// + the barrier chain make write-after-read impossible (a wave must pass
// ch+1's barrier, i.e. all waves finished ch's PV, before writing parity p
// again).
// Cost added: ~16 exp + 16 select + 16 pk-mul per lane-chunk (~100 cyc) vs
// ~1.5 kcyc convoy removed.
__global__ __launch_bounds__(512, 2) void flash_kernel(
    const _Float16* __restrict__ Qp, const _Float16* __restrict__ Kp,
    const _Float16* __restrict__ Vp, float* __restrict__ outp)
{
    __shared__ __align__(16) _Float16 Qls[16384];        // 32 KB: Q tile
    __shared__ __align__(16) _Float16 Ps[2][2][32][72];  // [parity][half][q][key]
    __shared__ float Smax2[2][32][12];                   // [parity][q][wave]
    __shared__ float Ssum2[2][32][12];
    __shared__ float lfin[32];

    const int tid  = threadIdx.x;
    const int w    = tid >> 6;          // 0..7
    const int lane = tid & 63;
    const int quad = lane >> 4;
    const int l16  = lane & 15;
    const int qbase = blockIdx.x * 32;

    // ---- stage Q tile (32 frags = 32 KB); LDS layout == global frag layout
    {
        const f16x8* src = (const f16x8*)(Qp + (size_t)qbase * 512);
        f16x8* dst = (f16x8*)Qls;
#pragma unroll
        for (int i = 0; i < 4; ++i)
            dst[tid + i * 512] = src[tid + i * 512];
    }

    // per-lane online stats for q0 = l16 and q1 = 16+l16 (duplicated across quads)
    float mreg0 = -1e30f, mreg1 = -1e30f, lreg0 = 0.0f, lreg1 = 0.0f;
    f32x4 oacc[2][4];
#pragma unroll
    for (int qt = 0; qt < 2; ++qt)
#pragma unroll
        for (int t = 0; t < 4; ++t) oacc[qt][t] = (f32x4)(0.0f);

    // ---- prologue: K frags for chunk 0 (wave's 16-key slice, full DK)
    const _Float16* kfp = Kp + (size_t)w * 16 * 512 + lane * 8;   // + ch*65536
    f16x8 kf[16];
#pragma unroll
    for (int stp = 0; stp < 16; ++stp)
        kf[stp] = *(const f16x8*)(kfp + (size_t)stp * 512);

    // Qls visible to all waves before first S (lgkm-only, no vmcnt drain)
    asm volatile("s_waitcnt lgkmcnt(0)" ::: "memory");
    __builtin_amdgcn_s_barrier();

    f16x8 vf[16];

    for (int ch = 0; ch < 64; ++ch) {
        const int p = ch & 1;

        // ---- issue V loads for THIS chunk (consumed at PV, 1 barrier away)
        const _Float16* vp = Vp + ((size_t)ch * 128 + w * 8) * 512 + lane * 8;
#pragma unroll
        for (int h = 0; h < 2; ++h)
#pragma unroll
            for (int t = 0; t < 4; ++t)
#pragma unroll
                for (int ks = 0; ks < 2; ++ks)
                    vf[h * 8 + t * 2 + ks] = *(const f16x8*)(vp + (size_t)(h * 64 + t * 2 + ks) * 512);

        // ---- S^T: 16 keys (wave slice) x 32 q; kf as A, Q frags as B
        f32x4 st0 = (f32x4)(0.0f), st1 = (f32x4)(0.0f);
        __builtin_amdgcn_s_setprio(1);
#pragma unroll
        for (int stp = 0; stp < 16; ++stp) {
            f16x8 q0 = *(const f16x8*)&Qls[(size_t)stp * 512 + lane * 8];
            f16x8 q1 = *(const f16x8*)&Qls[(size_t)(16 + stp) * 512 + lane * 8];
            st0 = __builtin_amdgcn_mfma_f32_16x16x32_f16(kf[stp], q0, st0, 0, 0, 0);
            st1 = __builtin_amdgcn_mfma_f32_16x16x32_f16(kf[stp], q1, st1, 0, 0, 0);
        }
        __builtin_amdgcn_s_setprio(0);
        // lane holds S[key = w*16 + quad*4 + r][q = band*16 + l16], r = 0..3

        // ---- per-wave slice max (NO cross-wave wait), P = exp(S - m_w)
        float ms0 = fmaxf(fmaxf(st0[0], st0[1]), fmaxf(st0[2], st0[3]));
        float ms1 = fmaxf(fmaxf(st1[0], st1[1]), fmaxf(st1[2], st1[3]));
        ms0 = fmaxf(ms0, __shfl_xor(ms0, 16)); ms0 = fmaxf(ms0, __shfl_xor(ms0, 32));
        ms1 = fmaxf(ms1, __shfl_xor(ms1, 16)); ms1 = fmaxf(ms1, __shfl_xor(ms1, 32));

        float p00 = __expf(st0[0] - ms0), p01 = __expf(st0[1] - ms0);
        float p02 = __expf(st0[2] - ms0), p03 = __expf(st0[3] - ms0);
        float p10 = __expf(st1[0] - ms1), p11 = __expf(st1[1] - ms1);
        float p12 = __expf(st1[2] - ms1), p13 = __expf(st1[3] - ms1);
        f16x4 pp0, pp1;
        pp0[0] = (_Float16)p00; pp0[1] = (_Float16)p01;
        pp0[2] = (_Float16)p02; pp0[3] = (_Float16)p03;
        pp1[0] = (_Float16)p10; pp1[1] = (_Float16)p11;
        pp1[2] = (_Float16)p12; pp1[3] = (_Float16)p13;
        *(f16x4*)&Ps[p][w >> 2][l16][(w & 3) * 16 + quad * 4]      = pp0;
        *(f16x4*)&Ps[p][w >> 2][16 + l16][(w & 3) * 16 + quad * 4] = pp1;

        float ts0 = (p00 + p01) + (p02 + p03);
        float ts1 = (p10 + p11) + (p12 + p13);
        ts0 += __shfl_xor(ts0, 16); ts0 += __shfl_xor(ts0, 32);
        ts1 += __shfl_xor(ts1, 16); ts1 += __shfl_xor(ts1, 32);
        if (lane < 16) {
            Smax2[p][lane][w] = ms0; Smax2[p][16 + lane][w] = ms1;
            Ssum2[p][lane][w] = ts0; Ssum2[p][16 + lane][w] = ts1;
        }

        // ---- prefetch next K (kf consumed by S^T above)
        if (ch + 1 < 64) {
            const _Float16* kp = kfp + (size_t)(ch + 1) * 65536;
#pragma unroll
            for (int stp = 0; stp < 16; ++stp)
                kf[stp] = *(const f16x8*)(kp + (size_t)stp * 512);
        }

        asm volatile("s_waitcnt lgkmcnt(0)" ::: "memory");
        __builtin_amdgcn_s_barrier();      // THE single barrier per chunk

        // ---- combine: read 8 wave maxes, global mn, correction scales
        float4 a0 = *(const float4*)&Smax2[p][l16][0];
        float4 b0 = *(const float4*)&Smax2[p][l16][4];
        float4 a1 = *(const float4*)&Smax2[p][16 + l16][0];
        float4 b1 = *(const float4*)&Smax2[p][16 + l16][4];
        float mt0 = fmaxf(fmaxf(fmaxf(a0.x, a0.y), fmaxf(a0.z, a0.w)),
                          fmaxf(fmaxf(b0.x, b0.y), fmaxf(b0.z, b0.w)));
        float mt1 = fmaxf(fmaxf(fmaxf(a1.x, a1.y), fmaxf(a1.z, a1.w)),
                          fmaxf(fmaxf(b1.x, b1.y), fmaxf(b1.z, b1.w)));
        float mn0 = fmaxf(mreg0, mt0);
        float mn1 = fmaxf(mreg1, mt1);
        float alpha0 = __expf(mreg0 - mn0); mreg0 = mn0;
        float alpha1 = __expf(mreg1 - mn1); mreg1 = mn1;

        float s0_0 = __expf(a0.x - mn0), s0_1 = __expf(a0.y - mn0);
        float s0_2 = __expf(a0.z - mn0), s0_3 = __expf(a0.w - mn0);
        float s0_4 = __expf(b0.x - mn0), s0_5 = __expf(b0.y - mn0);
        float s0_6 = __expf(b0.z - mn0), s0_7 = __expf(b0.w - mn0);
        float s1_0 = __expf(a1.x - mn1), s1_1 = __expf(a1.y - mn1);
        float s1_2 = __expf(a1.z - mn1), s1_3 = __expf(a1.w - mn1);
        float s1_4 = __expf(b1.x - mn1), s1_5 = __expf(b1.y - mn1);
        float s1_6 = __expf(b1.z - mn1), s1_7 = __expf(b1.w - mn1);

        float4 sa = *(const float4*)&Ssum2[p][l16][0];
        float4 sb = *(const float4*)&Ssum2[p][l16][4];
        float4 sc4 = *(const float4*)&Ssum2[p][16 + l16][0];
        float4 sd4 = *(const float4*)&Ssum2[p][16 + l16][4];
        lreg0 = lreg0 * alpha0 + (s0_0 * sa.x + s0_1 * sa.y + s0_2 * sa.z + s0_3 * sa.w)
                               + (s0_4 * sb.x + s0_5 * sb.y + s0_6 * sb.z + s0_7 * sb.w);
        lreg1 = lreg1 * alpha1 + (s1_0 * sc4.x + s1_1 * sc4.y + s1_2 * sc4.z + s1_3 * sc4.w)
                               + (s1_4 * sd4.x + s1_5 * sd4.y + s1_6 * sd4.z + s1_7 * sd4.w);

        // ---- carry alpha to oacc rows (q = quad*4 + g): src lane = quad*20+g
        float ao0[4], ao1[4];
#pragma unroll
        for (int g = 0; g < 4; ++g) {
            ao0[g] = __shfl(alpha0, quad * 20 + g);
            ao1[g] = __shfl(alpha1, quad * 20 + g);
        }
#pragma unroll
        for (int t = 0; t < 4; ++t)
#pragma unroll
            for (int g = 0; g < 4; ++g) {
                oacc[0][t][g] *= ao0[g];
                oacc[1][t][g] *= ao1[g];
            }

        // ---- PV with per-fragment correction: pa cols of kst come from
        // source wave w' = 2*kst + (lane>=32); scale = exp(m_w' - mn)
        const bool hi = (lane & 32) != 0;
        const _Float16 c00 = (_Float16)(hi ? s0_1 : s0_0);
        const _Float16 c01 = (_Float16)(hi ? s0_3 : s0_2);
        const _Float16 c02 = (_Float16)(hi ? s0_5 : s0_4);
        const _Float16 c03 = (_Float16)(hi ? s0_7 : s0_6);
        const _Float16 c10 = (_Float16)(hi ? s1_1 : s1_0);
        const _Float16 c11 = (_Float16)(hi ? s1_3 : s1_2);
        const _Float16 c12 = (_Float16)(hi ? s1_5 : s1_4);
        const _Float16 c13 = (_Float16)(hi ? s1_7 : s1_6);

        __builtin_amdgcn_s_setprio(1);
#pragma unroll
        for (int kst = 0; kst < 4; ++kst) {
            const _Float16 sA = (kst == 0) ? c00 : (kst == 1) ? c01 : (kst == 2) ? c02 : c03;
            const _Float16 sB = (kst == 0) ? c10 : (kst == 1) ? c11 : (kst == 2) ? c12 : c13;
            f16x8 pa0 = *(const f16x8*)&Ps[p][kst >> 1][l16][(kst & 1) * 32 + quad * 8];
            f16x8 pa1 = *(const f16x8*)&Ps[p][kst >> 1][16 + l16][(kst & 1) * 32 + quad * 8];
            pa0 = pa0 * sA;
            pa1 = pa1 * sB;
            const int vb = (kst >> 1) * 8 + (kst & 1);
#pragma unroll
            for (int t = 0; t < 4; ++t) {
                oacc[0][t] = __builtin_amdgcn_mfma_f32_16x16x32_f16(pa0, vf[vb + t * 2], oacc[0][t], 0, 0, 0);
                oacc[1][t] = __builtin_amdgcn_mfma_f32_16x16x32_f16(pa1, vf[vb + t * 2], oacc[1][t], 0, 0, 0);
            }
        }
        __builtin_amdgcn_s_setprio(0);
    }

    // ---- epilogue: transpose l (stats live at q=l16; O rows are q=quad*4+g)
    if (w == 0 && lane < 16) { lfin[lane] = lreg0; lfin[16 + lane] = lreg1; }
    __syncthreads();

    const float norm = 0.044194173824159216f;   // 1/sqrt(512)
#pragma unroll
    for (int qt = 0; qt < 2; ++qt)
#pragma unroll
        for (int g = 0; g < 4; ++g) {
            const int row = qbase + qt * 16 + quad * 4 + g;
            const float sc = norm / lfin[qt * 16 + quad * 4 + g];
#pragma unroll
            for (int t = 0; t < 4; ++t)
                outp[(size_t)row * 512 + w * 64 + t * 16 + l16] = oacc[qt][t][g] * sc;
        }
}

extern "C" void kernel_launch(void* const* d_in, const int* in_sizes, int n_in,
                              void* d_out, int out_size, void* d_ws, size_t ws_size,
                              hipStream_t stream) {
    const float* q  = (const float*)d_in[0];
    const float* k  = (const float*)d_in[1];
    const float* v  = (const float*)d_in[2];
    const float* Wq = (const float*)d_in[3];
    const float* bq = (const float*)d_in[4];
    const float* Wk = (const float*)d_in[5];
    const float* bk = (const float*)d_in[6];
    const float* Wv = (const float*)d_in[7];
    const float* bv = (const float*)d_in[8];

    _Float16* Qp = (_Float16*)d_ws;                 // 8 MB, frag-major
    _Float16* Kp = Qp + (size_t)NQ * DK;            // 8 MB, frag-major
    _Float16* Vp = Kp + (size_t)NKV * DK;           // 8 MB, frag-major
    float* outp = (float*)d_out;

    proj_kernel<<<dim3(DK / 128, NQ / 128, 3), 256, 0, stream>>>(
        q, k, v, Wq, bq, Wk, bk, Wv, bv, Qp, Kp, Vp);
    flash_kernel<<<dim3(NQ / 32), 512, 0, stream>>>(Qp, Kp, Vp, outp);
}